// Round 9
// baseline (172.516 us; speedup 1.0000x reference)
//
#include <hip/hip_runtime.h>

typedef __attribute__((ext_vector_type(8))) short short8;
typedef __attribute__((ext_vector_type(16))) float f32x16;

// ws layout:
//   Ft2  [z=512][yy=66][xx=66][8] bf16 halo-padded features, z = c*8 + b   (35.68 MB)
//   wt   [i=576][n=128][8] bf16 chunk-major B                              (1.18 MB)
#define FT2_SHORTS (512u * 4356u * 8u)
#define PLANE16    4356
#define BUFB       36864          // one LDS buffer: A 24576 B + B 12288 B

typedef __attribute__((address_space(3))) unsigned int lds_u32_t;
typedef __attribute__((address_space(1))) const unsigned int g_u32_t;

__device__ __forceinline__ unsigned short f2bf(float x) {
    union { float f; unsigned u; } v; v.f = x;
    unsigned r = v.u + 0x7FFFu + ((v.u >> 16) & 1u);   // RNE bf16
    return (unsigned short)(r >> 16);
}

__device__ __forceinline__ void feat8(float p, unsigned short* uf) {
    float e   = __expf(-p);
    float sig = 1.f / (1.f + e);
    uf[0] = f2bf(p * sig);
    float u  = p * 1.5f + 4.5f;
    float fj = floorf(u);
    int   j0 = (int)fj;
    float t  = u - fj;
    bool  inr = (u >= 0.f) && (u < 9.f);
    float t2 = t * t, t3 = t2 * t;
    const float c16 = 1.f / 6.f;
    float r0 = t3 * c16;
    float r1 = (-3.f * t3 + 3.f * t2 + 3.f * t + 1.f) * c16;
    float r2 = (3.f * t3 - 6.f * t2 + 4.f) * c16;
    float s1 = 1.f - t;
    float r3 = s1 * s1 * s1 * c16;
#pragma unroll
    for (int g = 0; g < 6; ++g) {
        int r = j0 - g;
        float v = (r == 0) ? r0 : ((r == 1) ? r1 : ((r == 2) ? r2 : ((r == 3) ? r3 : 0.f)));
        uf[1 + g] = f2bf(inr ? v : 0.f);
    }
    uf[7] = 0;
}

// ---- Fused prep: per block (512): 144 B-chunks + 1 halo plane + 1 feature line ----
__global__ __launch_bounds__(256)
void prep_all(const float* __restrict__ x,
              const float* __restrict__ bw, const float* __restrict__ sw,
              unsigned short* __restrict__ ft, unsigned short* __restrict__ wt) {
    const int blk = blockIdx.x;          // 0..511
    const int tid = threadIdx.x;

    // (1) B prep, chunk-major: wt[(i*128 + o)*8 + f]
    if (tid < 144) {
        int idx = blk * 144 + tid;
        int o = idx / 576;
        int i = idx - o * 576;
        union { unsigned short u[8]; uint4 v; } pk;
        pk.u[0] = f2bf(bw[o * 576 + i]);
        const float* s = sw + (size_t)(o * 576 + i) * 6;
#pragma unroll
        for (int f = 0; f < 6; ++f) pk.u[1 + f] = f2bf(s[f]);
        pk.u[7] = 0;
        *(uint4*)(wt + ((size_t)(i * 128 + o) * 8)) = pk.v;
    }

    // (2) halo plane z = blk: feat8(0) into the 260 border cells
    {
        short8 pad = { 0, 0, (short)0x3CAB, (short)0x3EF5,
                       (short)0x3EF5, (short)0x3CAB, 0, 0 };
        for (int t = tid; t < 260; t += 256) {
            int yy, xx;
            if (t < 66)       { yy = 0;       xx = t; }
            else if (t < 132) { yy = 65;      xx = t - 66; }
            else if (t < 196) { yy = t - 131; xx = 0; }
            else              { yy = t - 195; xx = 65; }
            ((short8*)ft)[blk * PLANE16 + yy * 66 + xx] = pad;
        }
    }

    // (3) features for line = blk (b = blk>>6, y = blk&63)
    __shared__ float Xl[64 * 65];
    const int b = blk >> 6, y = blk & 63;
    const float* xl = x + (size_t)blk * 4096;
    for (int f4 = tid; f4 < 1024; f4 += 256) {
        float4 v = ((const float4*)xl)[f4];
        int xx = f4 >> 4, c4 = (f4 & 15) << 2;
        float* d = &Xl[xx * 65 + c4];
        d[0] = v.x; d[1] = v.y; d[2] = v.z; d[3] = v.w;
    }
    __syncthreads();
    const int xx = tid & 63;
    const int cw = tid >> 6;
#pragma unroll 4
    for (int p = 0; p < 16; ++p) {
        int c = cw + (p << 2);
        float pv = Xl[xx * 65 + c];
        union { unsigned short u[8]; uint4 v; } pk;
        feat8(pv, pk.u);
        size_t o16 = (size_t)(c * 8 + b) * PLANE16 + (y + 1) * 66 + (xx + 1);
        *(uint4*)(ft + (o16 << 3)) = pk.v;
    }
}

// ---- Main GEMM: grid 512 = 128 m-tiles x K-split 4; block 256 (4 waves = 4 lines) ----
// tile 256m(4 lines) x 128n; wave = 64m x 128n; acc 2ms x 4ns x f32x16 (128 VGPR).
// Slab = 6 chunks (K=48); LDS buf 36 KB = [A 6x256x16B | B 6x128x16B], double-buffered.
// Epilogue: f32 atomicAdd partials (4 K-splits), bias added by kk==0.
#define STAGE(sl)                                                                     \
  {                                                                                   \
    char* buf = smem + (((sl) & 1) ? BUFB : 0);                                       \
    _Pragma("unroll")                                                                 \
    for (int t = 0; t < 6; ++t) {                                                     \
        int idx = wave * 6 + t;                                                       \
        int e_  = idx >> 2;                                                           \
        int g2  = idx & 3;                                                            \
        int i_  = cbase + (sl) * 6 + e_;                                              \
        int c_  = (i_ * 7282) >> 16;                                                  \
        int i9_ = i_ - c_ * 9;                                                        \
        int kh_ = (i9_ * 11) >> 5;                                                    \
        int kw_ = i9_ - kh_ * 3;                                                      \
        const unsigned short* asrc = ft +                                             \
            (((size_t)(c_ * 8 + b) * PLANE16 + (y0 + g2 + kh_) * 66 + kw_) << 3)      \
            + lane * 8;                                                               \
        __builtin_amdgcn_global_load_lds((g_u32_t*)asrc,                              \
            (lds_u32_t*)(buf + (e_ * 256 + g2 * 64 + lane) * 16), 16, 0, 0);          \
    }                                                                                 \
    _Pragma("unroll")                                                                 \
    for (int j = 0; j < 3; ++j) {                                                     \
        int boff = (wave * 3 + j) * 1024 + lane * 16;                                 \
        const char* bsrc = (const char*)wt + (size_t)(cbase + (sl) * 6) * 2048 + boff;\
        __builtin_amdgcn_global_load_lds((g_u32_t*)bsrc,                              \
            (lds_u32_t*)(buf + 24576 + boff), 16, 0, 0);                              \
    }                                                                                 \
  }

#define KSTEP(s_)                                                                     \
  {                                                                                   \
    int cl = 2 * (s_) + h;                                                            \
    const char* Ab = bufr + (cl * 256 + wave * 64) * 16;                              \
    const char* Bb = bufr + 24576 + cl * 128 * 16;                                    \
    short8 a0 = *(const short8*)(Ab + l32 * 16);                                      \
    short8 a1 = *(const short8*)(Ab + (32 + l32) * 16);                               \
    short8 b0 = *(const short8*)(Bb + l32 * 16);                                      \
    short8 b1 = *(const short8*)(Bb + (32 + l32) * 16);                               \
    short8 b2 = *(const short8*)(Bb + (64 + l32) * 16);                               \
    short8 b3 = *(const short8*)(Bb + (96 + l32) * 16);                               \
    acc00 = __builtin_amdgcn_mfma_f32_32x32x16_bf16(a0, b0, acc00, 0, 0, 0);          \
    acc01 = __builtin_amdgcn_mfma_f32_32x32x16_bf16(a0, b1, acc01, 0, 0, 0);          \
    acc02 = __builtin_amdgcn_mfma_f32_32x32x16_bf16(a0, b2, acc02, 0, 0, 0);          \
    acc03 = __builtin_amdgcn_mfma_f32_32x32x16_bf16(a0, b3, acc03, 0, 0, 0);          \
    acc10 = __builtin_amdgcn_mfma_f32_32x32x16_bf16(a1, b0, acc10, 0, 0, 0);          \
    acc11 = __builtin_amdgcn_mfma_f32_32x32x16_bf16(a1, b1, acc11, 0, 0, 0);          \
    acc12 = __builtin_amdgcn_mfma_f32_32x32x16_bf16(a1, b2, acc12, 0, 0, 0);          \
    acc13 = __builtin_amdgcn_mfma_f32_32x32x16_bf16(a1, b3, acc13, 0, 0, 0);          \
  }

__global__ __launch_bounds__(256, 2)
void convkan_gemm(const unsigned short* __restrict__ ft,
                  const unsigned short* __restrict__ wt,
                  const float* __restrict__ bias,
                  float* __restrict__ out) {
    extern __shared__ char smem[];               // 2 x 36 KB

    const int tid  = threadIdx.x;
    const int blk  = blockIdx.x;                 // 512
    const int kk   = blk & 3;                    // K-split quarter
    const int mb   = blk >> 2;                   // 0..127, 4 lines each
    const int lane = tid & 63;
    const int wave = tid >> 6;                   // 0..3 = line within tile
    const int l32  = lane & 31;
    const int h    = lane >> 5;                  // k-half

    const int b  = mb >> 4;
    const int y0 = (mb & 15) << 2;
    const int cbase = kk * 144;                  // chunk range [cbase, cbase+144)

    f32x16 acc00, acc01, acc02, acc03, acc10, acc11, acc12, acc13;
#pragma unroll
    for (int e = 0; e < 16; ++e) {
        acc00[e] = 0.f; acc01[e] = 0.f; acc02[e] = 0.f; acc03[e] = 0.f;
        acc10[e] = 0.f; acc11[e] = 0.f; acc12[e] = 0.f; acc13[e] = 0.f;
    }

    STAGE(0);
    for (int it = 0; it < 24; ++it) {
        __syncthreads();                         // drains slab(it)'s DMA
        if (it + 1 < 24) STAGE(it + 1);          // lands during this compute phase
        const char* bufr = smem + ((it & 1) ? BUFB : 0);
        KSTEP(0) KSTEP(1) KSTEP(2)
    }

    // epilogue: C/D row = (r&3)+8*(r>>2)+4*h (+ms*32), col = l32 (+ns*32)
    float bv[4];
#pragma unroll
    for (int ns = 0; ns < 4; ++ns) bv[ns] = (kk == 0) ? bias[ns * 32 + l32] : 0.f;
    const int prow = mb * 256 + wave * 64;       // global pixel base for this wave
#pragma unroll
    for (int r = 0; r < 16; ++r) {
        int mloc = (r & 3) + ((r >> 2) << 3) + 4 * h;
        float* p0 = out + (size_t)(prow + mloc) * 128 + l32;
        float* p1 = out + (size_t)(prow + 32 + mloc) * 128 + l32;
        atomicAdd(p0,      acc00[r] + bv[0]);
        atomicAdd(p0 + 32, acc01[r] + bv[1]);
        atomicAdd(p0 + 64, acc02[r] + bv[2]);
        atomicAdd(p0 + 96, acc03[r] + bv[3]);
        atomicAdd(p1,      acc10[r] + bv[0]);
        atomicAdd(p1 + 32, acc11[r] + bv[1]);
        atomicAdd(p1 + 64, acc12[r] + bv[2]);
        atomicAdd(p1 + 96, acc13[r] + bv[3]);
    }
}

extern "C" void kernel_launch(void* const* d_in, const int* in_sizes, int n_in,
                              void* d_out, int out_size, void* d_ws, size_t ws_size,
                              hipStream_t stream) {
    (void)in_sizes; (void)n_in; (void)ws_size;
    const float* x        = (const float*)d_in[0];
    const float* base_w   = (const float*)d_in[1];
    const float* spline_w = (const float*)d_in[2];
    const float* bias     = (const float*)d_in[3];
    float* out = (float*)d_out;

    unsigned short* ft = (unsigned short*)d_ws;      // 35.68 MB halo features
    unsigned short* wt = ft + FT2_SHORTS;            // 1.18 MB chunk-major B

    hipMemsetAsync(out, 0, (size_t)out_size * sizeof(float), stream);
    hipLaunchKernelGGL(prep_all, dim3(512), dim3(256), 0, stream,
                       x, base_w, spline_w, ft, wt);

    const int shmem = 2 * BUFB;                      // 73728 B
    (void)hipFuncSetAttribute((const void*)convkan_gemm,
                              hipFuncAttributeMaxDynamicSharedMemorySize, shmem);
    hipLaunchKernelGGL(convkan_gemm, dim3(512), dim3(256), shmem, stream,
                       ft, wt, bias, out);
}

// Round 10
// 152.869 us; speedup vs baseline: 1.1285x; 1.1285x over previous
//
#include <hip/hip_runtime.h>

typedef __attribute__((ext_vector_type(8))) short short8;
typedef __attribute__((ext_vector_type(16))) float f32x16;

// ws layout:
//   Ft2  [z=512][yy=66][xx=66][8] bf16 halo-padded features, z = c*8 + b   (35.68 MB)
//   wt   [i=576][n=128][8] bf16 chunk-major B                              (1.18 MB)
#define FT2_SHORTS (512u * 4356u * 8u)
#define PLANE16    4356

typedef __attribute__((address_space(3))) unsigned int lds_u32_t;
typedef __attribute__((address_space(1))) const unsigned int g_u32_t;

__device__ __forceinline__ unsigned short f2bf(float x) {
    union { float f; unsigned u; } v; v.f = x;
    unsigned r = v.u + 0x7FFFu + ((v.u >> 16) & 1u);   // RNE bf16
    return (unsigned short)(r >> 16);
}

__device__ __forceinline__ void feat8(float p, unsigned short* uf) {
    float e   = __expf(-p);
    float sig = 1.f / (1.f + e);
    uf[0] = f2bf(p * sig);
    float u  = p * 1.5f + 4.5f;
    float fj = floorf(u);
    int   j0 = (int)fj;
    float t  = u - fj;
    bool  inr = (u >= 0.f) && (u < 9.f);
    float t2 = t * t, t3 = t2 * t;
    const float c16 = 1.f / 6.f;
    float r0 = t3 * c16;
    float r1 = (-3.f * t3 + 3.f * t2 + 3.f * t + 1.f) * c16;
    float r2 = (3.f * t3 - 6.f * t2 + 4.f) * c16;
    float s1 = 1.f - t;
    float r3 = s1 * s1 * s1 * c16;
#pragma unroll
    for (int g = 0; g < 6; ++g) {
        int r = j0 - g;
        float v = (r == 0) ? r0 : ((r == 1) ? r1 : ((r == 2) ? r2 : ((r == 3) ? r3 : 0.f)));
        uf[1 + g] = f2bf(inr ? v : 0.f);
    }
    uf[7] = 0;
}

// ---- Fused prep (512 blocks): zero out-slice + 144 B-chunks + halo plane + feature line
__global__ __launch_bounds__(256)
void prep_all(const float* __restrict__ x,
              const float* __restrict__ bw, const float* __restrict__ sw,
              unsigned short* __restrict__ ft, unsigned short* __restrict__ wt,
              float* __restrict__ out) {
    const int blk = blockIdx.x;          // 0..511
    const int tid = threadIdx.x;

    // (0) zero this block's output slice (rows blk*64 .. +64, 32 KB) — replaces memset launch
    {
        float4 z4 = make_float4(0.f, 0.f, 0.f, 0.f);
        float4* ob = (float4*)(out + (size_t)blk * 64 * 128);
        for (int t = tid; t < 2048; t += 256) ob[t] = z4;
    }

    // (1) B prep, chunk-major: wt[(i*128 + o)*8 + f]
    if (tid < 144) {
        int idx = blk * 144 + tid;
        int o = idx / 576;
        int i = idx - o * 576;
        union { unsigned short u[8]; uint4 v; } pk;
        pk.u[0] = f2bf(bw[o * 576 + i]);
        const float* s = sw + (size_t)(o * 576 + i) * 6;
#pragma unroll
        for (int f = 0; f < 6; ++f) pk.u[1 + f] = f2bf(s[f]);
        pk.u[7] = 0;
        *(uint4*)(wt + ((size_t)(i * 128 + o) * 8)) = pk.v;
    }

    // (2) halo plane z = blk: feat8(0) = {0,0,1/48,23/48,23/48,1/48,0,0}
    {
        short8 pad = { 0, 0, (short)0x3CAB, (short)0x3EF5,
                       (short)0x3EF5, (short)0x3CAB, 0, 0 };
        for (int t = tid; t < 260; t += 256) {
            int yy, xx;
            if (t < 66)       { yy = 0;       xx = t; }
            else if (t < 132) { yy = 65;      xx = t - 66; }
            else if (t < 196) { yy = t - 131; xx = 0; }
            else              { yy = t - 195; xx = 65; }
            ((short8*)ft)[blk * PLANE16 + yy * 66 + xx] = pad;
        }
    }

    // (3) features for line = blk (b = blk>>6, y = blk&63)
    __shared__ float Xl[64 * 65];
    const int b = blk >> 6, y = blk & 63;
    const float* xl = x + (size_t)blk * 4096;
    for (int f4 = tid; f4 < 1024; f4 += 256) {
        float4 v = ((const float4*)xl)[f4];
        int xx = f4 >> 4, c4 = (f4 & 15) << 2;
        float* d = &Xl[xx * 65 + c4];
        d[0] = v.x; d[1] = v.y; d[2] = v.z; d[3] = v.w;
    }
    __syncthreads();
    const int xx = tid & 63;
    const int cw = tid >> 6;
#pragma unroll 4
    for (int p = 0; p < 16; ++p) {
        int c = cw + (p << 2);
        float pv = Xl[xx * 65 + c];
        union { unsigned short u[8]; uint4 v; } pk;
        feat8(pv, pk.u);
        size_t o16 = (size_t)(c * 8 + b) * PLANE16 + (y + 1) * 66 + (xx + 1);
        *(uint4*)(ft + (o16 << 3)) = pk.v;
    }
}

// ---- Main GEMM: grid 512 = 256 m-tiles x K-split 2; block 256 (4 waves 2m x 2n) ----
// tile 128m(2 lines) x 128n; wave 64m x 64n; slab = 16 elems (K=128), 18 slabs.
// B: LDS via global_load_lds, double-buffered 2x32 KB. A: registers, direct global,
// double-buffered one slab ahead (loads pipeline across barriers via compiler vmcnt).
#define STAGE(sl)                                                                     \
  {                                                                                   \
    char* dst = (char*)Bs + (((sl) & 1) << 15) + epair * 16384 + bn * 16;             \
    const char* src = (const char*)wt + ((size_t)(ebase + (sl) * 16 + epair * 8)      \
                                         << 11) + bn * 16;                            \
    _Pragma("unroll")                                                                 \
    for (int j = 0; j < 8; ++j)                                                       \
        __builtin_amdgcn_global_load_lds((g_u32_t*)(src + j * 2048),                  \
                                         (lds_u32_t*)(dst + j * 2048), 16, 0, 0);     \
  }

#define ALOAD(sl, ARR)                                                                \
  {                                                                                   \
    _Pragma("unroll")                                                                 \
    for (int s_ = 0; s_ < 8; ++s_) {                                                  \
        int i_  = ebase + (sl) * 16 + 2 * s_ + h;                                     \
        int c_  = (i_ * 7282) >> 16;                                                  \
        int i9_ = i_ - c_ * 9;                                                        \
        int kh_ = (i9_ * 11) >> 5;                                                    \
        int kw_ = i9_ - kh_ * 3;                                                      \
        int t16 = c_ * (8 * PLANE16) + kh_ * 66 + kw_ + abase;                        \
        ARR[2 * s_]     = fptr[t16];                                                  \
        ARR[2 * s_ + 1] = fptr[t16 + 32];                                             \
    }                                                                                 \
  }

#define KSTEP(s_, ARR, bufp)                                                          \
  {                                                                                   \
    const char* Bb = (const char*)Bs + ((bufp) << 15) + (2 * (s_) + h) * 2048         \
                     + (nh * 64 + l32) * 16;                                          \
    short8 b0 = *(const short8*)(Bb);                                                 \
    short8 b1 = *(const short8*)(Bb + 512);                                           \
    acc00 = __builtin_amdgcn_mfma_f32_32x32x16_bf16(ARR[2*(s_)],   b0, acc00, 0,0,0); \
    acc01 = __builtin_amdgcn_mfma_f32_32x32x16_bf16(ARR[2*(s_)],   b1, acc01, 0,0,0); \
    acc10 = __builtin_amdgcn_mfma_f32_32x32x16_bf16(ARR[2*(s_)+1], b0, acc10, 0,0,0); \
    acc11 = __builtin_amdgcn_mfma_f32_32x32x16_bf16(ARR[2*(s_)+1], b1, acc11, 0,0,0); \
  }

#define KSTEPS(ARR, bufp) \
    KSTEP(0, ARR, bufp) KSTEP(1, ARR, bufp) KSTEP(2, ARR, bufp) KSTEP(3, ARR, bufp) \
    KSTEP(4, ARR, bufp) KSTEP(5, ARR, bufp) KSTEP(6, ARR, bufp) KSTEP(7, ARR, bufp)

__global__ __launch_bounds__(256, 2)
void convkan_gemm(const unsigned short* __restrict__ ft,
                  const unsigned short* __restrict__ wt,
                  const float* __restrict__ bias,
                  float* __restrict__ out) {
    __shared__ unsigned short Bs[2 * 16 * 128 * 8];   // 2 x 32 KB B slabs (16 elems each)

    const int tid  = threadIdx.x;
    const int blk  = blockIdx.x;                 // 512
    const int kk   = blk & 1;                    // K-half
    const int mb   = blk >> 1;                   // 0..255, 2 lines each
    const int lane = tid & 63;
    const int wave = tid >> 6;
    const int g    = wave >> 1;                  // line within tile
    const int nh   = wave & 1;                   // n-half
    const int l32  = lane & 31;
    const int h    = lane >> 5;                  // k-half (elem parity)

    const int b  = mb >> 5;
    const int y0 = (mb & 31) << 1;
    const int ebase = kk * 288;                  // elem range for this K-half

    const int abase = b * PLANE16 + (y0 + g) * 66 + l32;   // halo folds the -1
    const short8* fptr = (const short8*)ft;

    const int bn    = tid & 127;                 // B staging: n index
    const int epair = tid >> 7;                  // 0..1 -> elems 0..7 / 8..15

    f32x16 acc00, acc01, acc10, acc11;
#pragma unroll
    for (int e = 0; e < 16; ++e) { acc00[e] = 0.f; acc01[e] = 0.f; acc10[e] = 0.f; acc11[e] = 0.f; }

    short8 aA[16], aB[16];
    STAGE(0);
    ALOAD(0, aA);

    for (int it = 0; it < 18; it += 2) {
        __syncthreads();                         // B(it) resident in buf0
        STAGE(it + 1);                           // it+1 <= 17
        ALOAD(it + 1, aB);
        KSTEPS(aA, 0)
        __syncthreads();                         // B(it+1) resident in buf1
        if (it + 2 < 18) {
            STAGE(it + 2);
            ALOAD(it + 2, aA);
        }
        KSTEPS(aB, 1)
    }

    // epilogue: C/D row = (r&3)+8*(r>>2)+4*h (+ms*32), col = l32 (+ns*32); atomics
    const float bv0 = kk ? 0.f : bias[nh * 64 + l32];
    const float bv1 = kk ? 0.f : bias[nh * 64 + 32 + l32];
    const int prow = (mb * 2 + g) * 64;
    const int ncol = nh * 64 + l32;
#pragma unroll
    for (int r = 0; r < 16; ++r) {
        int mrow = (r & 3) + ((r >> 2) << 3) + 4 * h;
        float* p0 = out + (size_t)(prow + mrow) * 128 + ncol;
        float* p1 = out + (size_t)(prow + 32 + mrow) * 128 + ncol;
        atomicAdd(p0,      acc00[r] + bv0);
        atomicAdd(p0 + 32, acc01[r] + bv1);
        atomicAdd(p1,      acc10[r] + bv0);
        atomicAdd(p1 + 32, acc11[r] + bv1);
    }
}

extern "C" void kernel_launch(void* const* d_in, const int* in_sizes, int n_in,
                              void* d_out, int out_size, void* d_ws, size_t ws_size,
                              hipStream_t stream) {
    (void)in_sizes; (void)n_in; (void)out_size; (void)ws_size;
    const float* x        = (const float*)d_in[0];
    const float* base_w   = (const float*)d_in[1];
    const float* spline_w = (const float*)d_in[2];
    const float* bias     = (const float*)d_in[3];
    float* out = (float*)d_out;

    unsigned short* ft = (unsigned short*)d_ws;      // 35.68 MB halo features
    unsigned short* wt = ft + FT2_SHORTS;            // 1.18 MB chunk-major B

    hipLaunchKernelGGL(prep_all, dim3(512), dim3(256), 0, stream,
                       x, base_w, spline_w, ft, wt, out);
    hipLaunchKernelGGL(convkan_gemm, dim3(512), dim3(256), 0, stream,
                       ft, wt, bias, out);
}